// Round 7
// baseline (87.294 us; speedup 1.0000x reference)
//
#include <hip/hip_runtime.h>
#include <math.h>

#define T_TOK 8192
#define HID   2880
#define NE    128
#define TOPK  4
#define BK    64
#define NK    (HID / BK)      // 45 K-steps of 64
#define TM    32
#define LROW  72              // halves per x-row per plane (64 + 8 pad): b128 frag reads 2-way (free)
#define LPLANE (TM * LROW)    // 2304 halves per plane
#define LCOL  132             // logits LDS row stride (floats)

typedef _Float16 f16x8 __attribute__((ext_vector_type(8)));
typedef _Float16 f16x4 __attribute__((ext_vector_type(4)));
typedef float    f32x4 __attribute__((ext_vector_type(4)));

// ---------------------------------------------------------------------------
// Kernel 0: W (fp32) -> fragment-linear fp16 hi/lo planes, scaled x32 (keeps
// lo out of denormals; 2^-5 folded into the fused epilogue). Fragment
// (k-step gs32, expert-group j, plane p) at ((gs32*8+j)*2+p)*512 halves;
// lane l=(oct<<4)|(n&15) holds 8 k-consecutive halves = mfma_16x16x32 B chunk.
// ---------------------------------------------------------------------------
__global__ __launch_bounds__(256) void convert_w(const float* __restrict__ w,
                                                 _Float16* __restrict__ wc) {
  const int c = blockIdx.x * 256 + threadIdx.x;   // one 8-k chunk of one expert
  if (c >= NE * (HID / 8)) return;
  const int n  = c / (HID / 8);
  const int k8 = c % (HID / 8);
  const float4 v0 = *(const float4*)(w + (size_t)n * HID + k8 * 8);
  const float4 v1 = *(const float4*)(w + (size_t)n * HID + k8 * 8 + 4);
  const float f[8] = {v0.x, v0.y, v0.z, v0.w, v1.x, v1.y, v1.z, v1.w};
  f16x8 h, l;
#pragma unroll
  for (int i = 0; i < 8; ++i) {
    const float s = f[i] * 32.0f;
    const _Float16 hi = (_Float16)s;
    h[i] = hi;
    l[i] = (_Float16)(s - (float)hi);
  }
  const int gs   = k8 >> 2;
  const int oct  = k8 & 3;
  const int j    = n >> 4;
  const int lane = (oct << 4) | (n & 15);
  _Float16* base = wc + ((size_t)(gs * 8 + j) * 2) * 512 + lane * 8;
  *(f16x8*)(base)       = h;
  *(f16x8*)(base + 512) = l;
}

// ---------------------------------------------------------------------------
// Kernel 1: FUSED router. Tile 32 tokens x 128 experts, FULL K per block ->
// block owns complete logit rows -> top-4/softmax fused in epilogue via LDS.
// fp16x2 MFMA emulation of fp32 (xh*wh + xl*wh + xh*wl, *2^-5). 512 threads,
// 8 waves (2 token-halves x 4 expert-quarters), 2 frags/wave, BK=64.
// x prefetched 2 steps ahead (HBM), B 1 step ahead (L2-hot). No partials.
// ---------------------------------------------------------------------------
struct BFrag { f16x8 h[2][2], l[2][2]; };   // [expert-group g][k-chunk kc]

__device__ __forceinline__ void load_b(const _Float16* __restrict__ wc, int wn,
                                       int lane, int gs, BFrag& f) {
#pragma unroll
  for (int g = 0; g < 2; ++g)
#pragma unroll
    for (int kc = 0; kc < 2; ++kc) {
      const int gs32 = 2 * gs + kc;
      const _Float16* bp = wc + ((size_t)(gs32 * 8 + wn * 2 + g) * 2) * 512 + lane * 8;
      f.h[g][kc] = *(const f16x8*)bp;
      f.l[g][kc] = *(const f16x8*)(bp + 512);
    }
}

__device__ __forceinline__ void stage_x(const float4& v, _Float16* __restrict__ buf,
                                        int r, int kq) {
  const float a[4] = {v.x, v.y, v.z, v.w};
  f16x4 h, l;
#pragma unroll
  for (int i = 0; i < 4; ++i) {
    const _Float16 hi = (_Float16)a[i];
    h[i] = hi;
    l[i] = (_Float16)(a[i] - (float)hi);
  }
  const int off = r * LROW + kq * 4;
  *(f16x4*)&buf[off]          = h;
  *(f16x4*)&buf[LPLANE + off] = l;
}

__device__ __forceinline__ void mfma_step(const _Float16* __restrict__ buf,
                                          const BFrag& f, int wm, int lane,
                                          f32x4 (&acc)[2]) {
#pragma unroll
  for (int kc = 0; kc < 2; ++kc) {
    const int off = (wm * 16 + (lane & 15)) * LROW + kc * 32 + (lane >> 4) * 8;
    const f16x8 ah = *(const f16x8*)&buf[off];
    const f16x8 al = *(const f16x8*)&buf[LPLANE + off];
#pragma unroll
    for (int g = 0; g < 2; ++g) {
      acc[g] = __builtin_amdgcn_mfma_f32_16x16x32_f16(ah, f.h[g][kc], acc[g], 0, 0, 0);
      acc[g] = __builtin_amdgcn_mfma_f32_16x16x32_f16(al, f.h[g][kc], acc[g], 0, 0, 0);
      acc[g] = __builtin_amdgcn_mfma_f32_16x16x32_f16(ah, f.l[g][kc], acc[g], 0, 0, 0);
    }
  }
}

__global__ __launch_bounds__(512) void logits_fused(const float* __restrict__ x,
                                                    const _Float16* __restrict__ wc,
                                                    const float* __restrict__ bias,
                                                    float* __restrict__ out) {
  __shared__ union {
    _Float16 stage[2][2][LPLANE];   // [buf][plane][row*LROW] = 18432 B
    float    logits[TM * LCOL];     // 16896 B (aliased; barrier-protected)
  } sh;

  const int t    = threadIdx.x;
  const int lane = t & 63;
  const int wv   = t >> 6;      // 0..7
  const int wm   = wv >> 2;     // token half
  const int wn   = wv & 3;      // expert quarter (32 experts)
  const int m0   = blockIdx.x * TM;
  const int r    = t >> 4;      // staging row 0..31
  const int kq   = t & 15;      // staging k-quad

  const float* xrow = x + (size_t)(m0 + r) * HID + kq * 4;

  f32x4 acc[2] = {};
  float4 xrA, xrB;
  BFrag bA, bB;

  // prologue: step0 staged; x(step1) in flight; B(0) in regs
  xrA = *(const float4*)(xrow);
  load_b(wc, wn, lane, 0, bA);
  stage_x(xrA, &sh.stage[0][0][0], r, kq);
  xrB = *(const float4*)(xrow + BK);
  __syncthreads();

  int st = 0;
  for (;;) {
    // even slot: compute buf0/bA; stage st+1 -> buf1
    if (st + 1 < NK) load_b(wc, wn, lane, st + 1, bB);
    if (st + 2 < NK) xrA = *(const float4*)(xrow + (st + 2) * BK);
    mfma_step(&sh.stage[0][0][0], bA, wm, lane, acc);
    if (st + 1 < NK) stage_x(xrB, &sh.stage[1][0][0], r, kq);
    __syncthreads();
    if (st + 1 >= NK) break;

    // odd slot: compute buf1/bB; stage st+2 -> buf0
    if (st + 2 < NK) load_b(wc, wn, lane, st + 2, bA);
    if (st + 3 < NK) xrB = *(const float4*)(xrow + (st + 3) * BK);
    mfma_step(&sh.stage[1][0][0], bB, wm, lane, acc);
    if (st + 2 < NK) stage_x(xrA, &sh.stage[0][0][0], r, kq);
    __syncthreads();
    st += 2;
    if (st >= NK) break;
  }

  // ---- fused epilogue: logits (+bias, unscale) -> LDS ----
  // C/D layout: col = lane&15 (expert), row = (lane>>4)*4 + reg (token)
  const int row0 = wm * 16 + (lane >> 4) * 4;
  const int col0 = wn * 32 + (lane & 15);
#pragma unroll
  for (int g = 0; g < 2; ++g) {
    const float bv = bias[col0 + g * 16];
#pragma unroll
    for (int rr = 0; rr < 4; ++rr)
      sh.logits[(row0 + rr) * LCOL + col0 + g * 16] = acc[g][rr] * 0.03125f + bv;
  }
  __syncthreads();

  // ---- per-wave top-4 (desc, lower-index tie-break = jax.lax.top_k),
  // softmax over the 4; each wave handles 4 of the 32 tokens ----
#pragma unroll
  for (int i = 0; i < 4; ++i) {
    const int tk = wv * 4 + i;
    float v0 = sh.logits[tk * LCOL + lane];
    float v1 = sh.logits[tk * LCOL + 64 + lane];
    const int i0 = lane, i1 = lane + 64;

    float topv[TOPK];
    int   topi[TOPK];
#pragma unroll
    for (int rr = 0; rr < TOPK; ++rr) {
      float bv; int bi;
      if (v0 >= v1) { bv = v0; bi = i0; }   // i0 < i1 implements the tie-break
      else          { bv = v1; bi = i1; }
#pragma unroll
      for (int off = 32; off > 0; off >>= 1) {
        const float ov = __shfl_xor(bv, off);
        const int   oi = __shfl_xor(bi, off);
        if (ov > bv || (ov == bv && oi < bi)) { bv = ov; bi = oi; }
      }
      topv[rr] = bv; topi[rr] = bi;
      if (bi == i0) v0 = -INFINITY;
      if (bi == i1) v1 = -INFINITY;
    }

    const float m = topv[0];
    float sum = 0.f;
#pragma unroll
    for (int rr = 0; rr < TOPK; ++rr) sum += expf(topv[rr] - m);

    if (lane < TOPK) {
      const int tok = m0 + tk;
      out[(size_t)tok * TOPK + lane] = expf(topv[lane] - m) / sum;
      out[(size_t)T_TOK * TOPK + (size_t)tok * TOPK + lane] = (float)topi[lane];
    }
  }
}

// ---------------------------------------------------------------------------
// Kernel 2: expert histogram, atomic-free & deterministic (R5 lesson: 32768
// contended cross-XCD atomics cost ~80 us). One block per expert scans the
// 32768 index floats (128 KB, L2-resident). Writes counts[e] directly.
// ---------------------------------------------------------------------------
__global__ __launch_bounds__(256) void count_kernel(const float* __restrict__ idxf,
                                                    float* __restrict__ counts) {
  const int e = blockIdx.x;
  const int t = threadIdx.x;
  const float ef = (float)e;
  int c = 0;
  for (int i = t; i < T_TOK * TOPK; i += 256)
    c += (idxf[i] == ef) ? 1 : 0;
#pragma unroll
  for (int off = 32; off > 0; off >>= 1) c += __shfl_xor(c, off);
  __shared__ int shred[4];
  if ((t & 63) == 0) shred[t >> 6] = c;
  __syncthreads();
  if (t == 0) counts[e] = (float)(shred[0] + shred[1] + shred[2] + shred[3]);
}

extern "C" void kernel_launch(void* const* d_in, const int* in_sizes, int n_in,
                              void* d_out, int out_size, void* d_ws, size_t ws_size,
                              hipStream_t stream) {
  const float* x    = (const float*)d_in[0];
  const float* w    = (const float*)d_in[1];
  const float* bias = (const float*)d_in[2];
  float* out = (float*)d_out;
  _Float16* wc = (_Float16*)d_ws;   // 1.44 MB fragment-linear W planes

  convert_w<<<(NE * (HID / 8) + 255) / 256, 256, 0, stream>>>(w, wc);
  logits_fused<<<T_TOK / TM, 512, 0, stream>>>(x, wc, bias, out);
  count_kernel<<<NE, 256, 0, stream>>>(out + (size_t)T_TOK * TOPK,
                                       out + 2 * (size_t)T_TOK * TOPK);
}

// Round 8
// 60.710 us; speedup vs baseline: 1.4379x; 1.4379x over previous
//
#include <hip/hip_runtime.h>
#include <math.h>

#define T_TOK 8192
#define HID   2880
#define NE    128
#define TOPK  4
#define NKS   (HID / 32)     // 90 K-steps of 32
#define TM    64             // tokens per tile
#define SPLITK 4
#define LROW  40             // LDS row stride in halves (80 B)
#define LPLANE (TM * LROW)   // one h- or l-plane, in halves (2560)

typedef _Float16 f16x8 __attribute__((ext_vector_type(8)));
typedef _Float16 f16x4 __attribute__((ext_vector_type(4)));
typedef float    f32x4 __attribute__((ext_vector_type(4)));

// ---------------------------------------------------------------------------
// Kernel 0: W (fp32) -> fragment-linear fp16 hi/lo planes, scaled x32 (keeps
// lo out of denormals; 2^-5 folded into the epilogue). Fragment (32-k step
// gs, expert-group j, plane p) at ((gs*8+j)*2+p)*512 halves; lane
// l=(oct<<4)|(n&15) holds 8 k-consecutive halves = mfma_16x16x32 B chunk.
// ---------------------------------------------------------------------------
__global__ __launch_bounds__(256) void convert_w(const float* __restrict__ w,
                                                 _Float16* __restrict__ wc) {
  const int c = blockIdx.x * 256 + threadIdx.x;   // one 8-k chunk of one expert
  if (c >= NE * (HID / 8)) return;
  const int n  = c / (HID / 8);
  const int k8 = c % (HID / 8);
  const float4 v0 = *(const float4*)(w + (size_t)n * HID + k8 * 8);
  const float4 v1 = *(const float4*)(w + (size_t)n * HID + k8 * 8 + 4);
  const float f[8] = {v0.x, v0.y, v0.z, v0.w, v1.x, v1.y, v1.z, v1.w};
  f16x8 h, l;
#pragma unroll
  for (int i = 0; i < 8; ++i) {
    const float s = f[i] * 32.0f;
    const _Float16 hi = (_Float16)s;
    h[i] = hi;
    l[i] = (_Float16)(s - (float)hi);
  }
  const int gs   = k8 >> 2;
  const int oct  = k8 & 3;
  const int j    = n >> 4;
  const int lane = (oct << 4) | (n & 15);
  _Float16* base = wc + ((size_t)(gs * 8 + j) * 2) * 512 + lane * 8;
  *(f16x8*)(base)       = h;
  *(f16x8*)(base + 512) = l;
}

// ---------------------------------------------------------------------------
// Kernel 1: partial logits via fp16x2 MFMA emulation of fp32:
// acc += xh*wh + xl*wh + xh*wl, *2^-5 at the end. Tile 64 tok x 128 exp,
// 4 waves (one 32-expert quarter each: mi=4 x nj=2 frags, 24 MFMA/32k-step,
// 170 B of B per MFMA). split-K=4 -> grid 512 (2 blocks/CU), planes 16 MB.
// Double-buffered LDS; x prefetched 2 steps ahead (HBM), B 1 ahead (L2-hot).
// XCD swizzle: s = bid&3 constant per die -> each XCD streams one wc chunk.
// ---------------------------------------------------------------------------
struct BF { f16x8 h[2], l[2]; };

__device__ __forceinline__ void load_b(const _Float16* __restrict__ wc, int wn,
                                       int lane, int gs, BF& f) {
#pragma unroll
  for (int g = 0; g < 2; ++g) {
    const _Float16* bp = wc + ((size_t)(gs * 8 + wn * 2 + g) * 2) * 512 + lane * 8;
    f.h[g] = *(const f16x8*)bp;
    f.l[g] = *(const f16x8*)(bp + 512);
  }
}

__device__ __forceinline__ void load_x(const float* __restrict__ x, int m0,
                                       int t, int gs, float4 (&xr)[2]) {
#pragma unroll
  for (int j = 0; j < 2; ++j) {
    const int c   = j * 256 + t;
    const int row = c >> 3;
    const int kq  = c & 7;
    xr[j] = *(const float4*)(x + (size_t)(m0 + row) * HID + gs * 32 + kq * 4);
  }
}

__device__ __forceinline__ void stage_x(const float4 (&xr)[2],
                                        _Float16* __restrict__ buf, int t) {
#pragma unroll
  for (int j = 0; j < 2; ++j) {
    const int c   = j * 256 + t;
    const int row = c >> 3;
    const int kq  = c & 7;
    const float a[4] = {xr[j].x, xr[j].y, xr[j].z, xr[j].w};
    f16x4 h, l;
#pragma unroll
    for (int i = 0; i < 4; ++i) {
      const _Float16 hi = (_Float16)a[i];
      h[i] = hi;
      l[i] = (_Float16)(a[i] - (float)hi);
    }
    const int off = row * LROW + kq * 4;
    *(f16x4*)&buf[off]          = h;
    *(f16x4*)&buf[LPLANE + off] = l;
  }
}

__device__ __forceinline__ void mfma_step(const _Float16* __restrict__ buf,
                                          const BF& f, int lane,
                                          f32x4 (&acc)[4][2]) {
#pragma unroll
  for (int mi = 0; mi < 4; ++mi) {
    const int off = (mi * 16 + (lane & 15)) * LROW + (lane >> 4) * 8;
    const f16x8 ah = *(const f16x8*)&buf[off];
    const f16x8 al = *(const f16x8*)&buf[LPLANE + off];
#pragma unroll
    for (int g = 0; g < 2; ++g) {
      acc[mi][g] = __builtin_amdgcn_mfma_f32_16x16x32_f16(ah, f.h[g], acc[mi][g], 0, 0, 0);
      acc[mi][g] = __builtin_amdgcn_mfma_f32_16x16x32_f16(al, f.h[g], acc[mi][g], 0, 0, 0);
      acc[mi][g] = __builtin_amdgcn_mfma_f32_16x16x32_f16(ah, f.l[g], acc[mi][g], 0, 0, 0);
    }
  }
}

__global__ __launch_bounds__(256, 2) void logits_mfma(const float* __restrict__ x,
                                                      const _Float16* __restrict__ wc,
                                                      float* __restrict__ part) {
  __shared__ _Float16 xsh[2 * 2 * LPLANE];   // [buf][plane][row*LROW] = 20480 B

  const int bid = blockIdx.x;
  // bijective swizzle over 512: s fixed per XCD (bid%8), tile spreads
  const int s    = bid & 3;
  const int tile = ((bid >> 3) << 1) | ((bid & 7) >> 2);
  const int m0   = tile * TM;

  const int t    = threadIdx.x;
  const int lane = t & 63;
  const int wn   = t >> 6;     // expert quarter (32 experts)

  const int kbase = NKS / SPLITK, krem = NKS % SPLITK;
  const int cnt   = kbase + (s < krem ? 1 : 0);
  const int st0   = s * kbase + (s < krem ? s : krem);

  _Float16* buf0 = xsh;
  _Float16* buf1 = xsh + 2 * LPLANE;

  f32x4 acc[4][2] = {};
  float4 xrA[2], xrB[2];
  BF bA, bB;

  // prologue: step 0 staged into buf0; x(step1) in flight; B(0) in regs
  load_x(x, m0, t, st0, xrA);
  load_b(wc, wn, lane, st0, bA);
  stage_x(xrA, buf0, t);
  if (cnt > 1) load_x(x, m0, t, st0 + 1, xrB);
  __syncthreads();

  int st = 0;
  for (;;) {
    // even slot: compute buf0/bA; stage st+1 -> buf1
    if (st + 1 < cnt) load_b(wc, wn, lane, st0 + st + 1, bB);
    if (st + 2 < cnt) load_x(x, m0, t, st0 + st + 2, xrA);
    mfma_step(buf0, bA, lane, acc);
    if (st + 1 < cnt) stage_x(xrB, buf1, t);
    __syncthreads();
    if (st + 1 >= cnt) break;

    // odd slot: compute buf1/bB; stage st+2 -> buf0
    if (st + 2 < cnt) load_b(wc, wn, lane, st0 + st + 2, bA);
    if (st + 3 < cnt) load_x(x, m0, t, st0 + st + 3, xrB);
    mfma_step(buf1, bB, lane, acc);
    if (st + 2 < cnt) stage_x(xrA, buf0, t);
    __syncthreads();
    st += 2;
    if (st >= cnt) break;
  }

  // epilogue: C/D layout col=lane&15 (expert), row=(lane>>4)*4+reg (token)
  float* pl = part + (size_t)s * T_TOK * NE;
  const int e0 = wn * 32 + (lane & 15);
  const int r0 = m0 + (lane >> 4) * 4;
#pragma unroll
  for (int mi = 0; mi < 4; ++mi)
#pragma unroll
    for (int g = 0; g < 2; ++g) {
      float* pp = pl + (size_t)(r0 + mi * 16) * NE + e0 + g * 16;
#pragma unroll
      for (int r = 0; r < 4; ++r) pp[(size_t)r * NE] = acc[mi][g][r] * 0.03125f;
    }
}

// ---------------------------------------------------------------------------
// Kernel 2: reduce split-K partials in fixed order + bias (float2/lane),
// per-token top-4 (desc, lower-index tie-break = jax.lax.top_k), softmax.
// NO atomics (R5 lesson: 32768 contended cross-XCD atomics ~80 us).
// One wave per token; lane holds experts {2l, 2l+1}.
// Out: [0,T*4) scores | [T*4,2*T*4) indices-as-float | [2*T*4,+128) counts
// ---------------------------------------------------------------------------
__global__ __launch_bounds__(256) void topk_kernel(const float* __restrict__ part,
                                                   const float* __restrict__ bias,
                                                   float* __restrict__ out) {
  const int lane = threadIdx.x & 63;
  const int wave = threadIdx.x >> 6;
  const int tok  = blockIdx.x * 4 + wave;

  float v0 = 0.f, v1 = 0.f;
#pragma unroll
  for (int s = 0; s < SPLITK; ++s) {   // fixed order -> deterministic
    const float2 p = ((const float2*)(part + ((size_t)s * T_TOK + tok) * NE))[lane];
    v0 += p.x;
    v1 += p.y;
  }
  const float2 b2 = ((const float2*)bias)[lane];
  v0 += b2.x;
  v1 += b2.y;
  const int i0 = 2 * lane, i1 = 2 * lane + 1;

  float topv[TOPK];
  int   topi[TOPK];

#pragma unroll
  for (int r = 0; r < TOPK; ++r) {
    float bv; int bi;
    if (v0 >= v1) { bv = v0; bi = i0; }   // i0 < i1 implements lower-index tie-break
    else          { bv = v1; bi = i1; }
#pragma unroll
    for (int off = 32; off > 0; off >>= 1) {
      const float ov = __shfl_xor(bv, off);
      const int   oi = __shfl_xor(bi, off);
      if (ov > bv || (ov == bv && oi < bi)) { bv = ov; bi = oi; }
    }
    topv[r] = bv; topi[r] = bi;
    if (bi == i0) v0 = -INFINITY;
    if (bi == i1) v1 = -INFINITY;
  }

  const float m = topv[0];
  float sum = 0.f;
#pragma unroll
  for (int r = 0; r < TOPK; ++r) sum += expf(topv[r] - m);

  if (lane < TOPK) {
    out[(size_t)tok * TOPK + lane] = expf(topv[lane] - m) / sum;
    out[(size_t)T_TOK * TOPK + (size_t)tok * TOPK + lane] = (float)topi[lane];
  }
}

// ---------------------------------------------------------------------------
// Kernel 3: expert histogram, atomic-free & deterministic. One block per
// expert scans the 32768 index floats (128 KB, L2-resident). Direct write.
// ---------------------------------------------------------------------------
__global__ __launch_bounds__(256) void count_kernel(const float* __restrict__ idxf,
                                                    float* __restrict__ counts) {
  const int e = blockIdx.x;
  const int t = threadIdx.x;
  const float ef = (float)e;
  int c = 0;
  for (int i = t; i < T_TOK * TOPK; i += 256)
    c += (idxf[i] == ef) ? 1 : 0;
#pragma unroll
  for (int off = 32; off > 0; off >>= 1) c += __shfl_xor(c, off);
  __shared__ int shred[4];
  if ((t & 63) == 0) shred[t >> 6] = c;
  __syncthreads();
  if (t == 0) counts[e] = (float)(shred[0] + shred[1] + shred[2] + shred[3]);
}

extern "C" void kernel_launch(void* const* d_in, const int* in_sizes, int n_in,
                              void* d_out, int out_size, void* d_ws, size_t ws_size,
                              hipStream_t stream) {
  const float* x    = (const float*)d_in[0];
  const float* w    = (const float*)d_in[1];
  const float* bias = (const float*)d_in[2];
  float* out  = (float*)d_out;
  float* part = (float*)d_ws;                                     // 4 planes, 16 MB
  _Float16* wc = (_Float16*)((char*)d_ws +
                             (size_t)SPLITK * T_TOK * NE * sizeof(float));

  convert_w<<<(NE * (HID / 8) + 255) / 256, 256, 0, stream>>>(w, wc);
  logits_mfma<<<(T_TOK / TM) * SPLITK, 256, 0, stream>>>(x, wc, part);
  topk_kernel<<<T_TOK / 4, 256, 0, stream>>>(part, bias, out);
  count_kernel<<<NE, 256, 0, stream>>>(out + (size_t)T_TOK * TOPK,
                                       out + 2 * (size_t)T_TOK * TOPK);
}